// Round 3
// baseline (521.540 us; speedup 1.0000x reference)
//
#include <hip/hip_runtime.h>
#include <hip/hip_bf16.h>

// ---------- helpers ----------
typedef __attribute__((ext_vector_type(8))) short bf16x8;
typedef __attribute__((ext_vector_type(4))) float f32x4;

static __device__ __forceinline__ short f2bf(float f) {
    unsigned u = __float_as_uint(f);
    unsigned r = (u + 0x7FFFu + ((u >> 16) & 1u)) >> 16;  // RNE
    return (short)(unsigned short)r;
}
static __device__ __forceinline__ float bf2f(short s) {
    return __uint_as_float(((unsigned)(unsigned short)s) << 16);
}

// async global->LDS, 16B per lane; LDS dest = wave-uniform base + lane*16 (m104)
static __device__ __forceinline__ void gload16(const void* g, void* l) {
    __builtin_amdgcn_global_load_lds((const __attribute__((address_space(1))) unsigned int*)g,
                                     (__attribute__((address_space(3))) unsigned int*)l, 16, 0, 0);
}

// pack 8 fp32 -> bf16x8 (RNE, packed cvt where available)
static __device__ __forceinline__ bf16x8 cvt8(const f32x4 lo, const f32x4 hi) {
    __hip_bfloat162 p0 = __float22bfloat162_rn(make_float2(lo[0], lo[1]));
    __hip_bfloat162 p1 = __float22bfloat162_rn(make_float2(lo[2], lo[3]));
    __hip_bfloat162 p2 = __float22bfloat162_rn(make_float2(hi[0], hi[1]));
    __hip_bfloat162 p3 = __float22bfloat162_rn(make_float2(hi[2], hi[3]));
    short2 s0 = *(short2*)&p0, s1 = *(short2*)&p1, s2 = *(short2*)&p2, s3 = *(short2*)&p3;
    bf16x8 r = {s0.x, s0.y, s1.x, s1.y, s2.x, s2.y, s3.x, s3.y};
    return r;
}

// ---------- degree ----------
__global__ void deg_kernel(const int* __restrict__ src, const int* __restrict__ dst,
                           int* __restrict__ deg_out, int* __restrict__ deg_in, int E) {
    int e = blockIdx.x * blockDim.x + threadIdx.x;
    if (e < E) {
        atomicAdd(&deg_out[src[e]], 1);
        atomicAdd(&deg_in[dst[e]], 1);
    }
}

// ---------- 3-phase multi-block exclusive scan of deg_in -> offsets ----------
__global__ void scan_part1(const int* __restrict__ deg, int* __restrict__ bsum, int N) {
    __shared__ int red[256];
    int i = blockIdx.x * 256 + threadIdx.x;
    red[threadIdx.x] = (i < N) ? deg[i] : 0;
    __syncthreads();
    for (int off = 128; off > 0; off >>= 1) {
        if (threadIdx.x < off) red[threadIdx.x] += red[threadIdx.x + off];
        __syncthreads();
    }
    if (threadIdx.x == 0) bsum[blockIdx.x] = red[0];
}

__global__ void scan_part2(const int* __restrict__ bsum, int* __restrict__ bsum_ex, int NB,
                           int* __restrict__ offsets, int N, int E) {
    __shared__ int s[256];
    int t = threadIdx.x;
    int v = (t < NB) ? bsum[t] : 0;
    s[t] = v;
    __syncthreads();
    for (int off = 1; off < 256; off <<= 1) {
        int u = (t >= off) ? s[t - off] : 0;
        __syncthreads();
        s[t] += u;
        __syncthreads();
    }
    bsum_ex[t] = s[t] - v;  // exclusive
    if (t == 0) offsets[N] = E;
}

// scan_part3 + fused norm computation (saves a launch)
__global__ void scan_part3(const int* __restrict__ deg_in, const int* __restrict__ deg_out,
                           const int* __restrict__ bsum_ex, int* __restrict__ offsets,
                           float* __restrict__ ns, float* __restrict__ nd, int N) {
    __shared__ int s[256];
    int t = threadIdx.x, i = blockIdx.x * 256 + t;
    int v = (i < N) ? deg_in[i] : 0;
    s[t] = v;
    __syncthreads();
    for (int off = 1; off < 256; off <<= 1) {
        int u = (t >= off) ? s[t - off] : 0;
        __syncthreads();
        s[t] += u;
        __syncthreads();
    }
    if (i < N) {
        offsets[i] = bsum_ex[blockIdx.x] + s[t] - v;
        ns[i] = rsqrtf((float)max(deg_out[i], 1));
        nd[i] = rsqrtf((float)max(v, 1));
    }
}

// ---------- scatter edges into CSR-by-dst buckets ----------
__global__ void scatter_kernel(const int* __restrict__ src, const int* __restrict__ dst,
                               const int* __restrict__ offsets, int* __restrict__ cursor,
                               int* __restrict__ bucket, int E) {
    int e = blockIdx.x * blockDim.x + threadIdx.x;
    if (e < E) {
        int d = dst[e];
        int p = atomicAdd(&cursor[d], 1);
        bucket[offsets[d] + p] = src[e];
    }
}

// ---------- W1 [K=1024][N=256] fp32 -> Wt [n][k] bf16 ----------
__global__ __launch_bounds__(1024) void transpose_w1(const float* __restrict__ W1,
                                                     short* __restrict__ Wt) {
    __shared__ short tile[32][33];
    int k0 = blockIdx.x * 32, n0 = blockIdx.y * 32;
    int tx = threadIdx.x & 31, ty = threadIdx.x >> 5;
    tile[ty][tx] = f2bf(W1[(size_t)(k0 + ty) * 256 + (n0 + tx)]);
    __syncthreads();
    Wt[(size_t)(n0 + ty) * 1024 + (k0 + tx)] = tile[tx][ty];
}

// ---------- GEMM1: hb = bf16((x @ W1) * norm_src[row]) ----------
// BN=256 = full output width -> x streamed from HBM exactly once.
// BM=64, 4 waves in 2x2 tiling, per-wave 32x128 (acc[2][8]).
// DOUBLE-BUFFERED staging (2-phase pipeline, T3-lite): issue next tile's
// global_load_lds BEFORE computing current tile; ONE barrier per K-step.
// A fp32 in LDS (XOR-swizzled 16B chunks), cvt->bf16 on read; B bf16 (XOR-swizzled);
// C staged through LDS for coalesced 16B/lane stores.
#define BM 64
#define BN 256
#define BK 32
#define NKT 32   // 1024 / BK
#define CSTR 264 // C-staging row stride in shorts (528B, 16B-divisible)

union SMem {
    struct {
        float A[2][BM * BK];  // 2 x 8 KB; row = 32 floats = 8 chunks of 16B, stored chunk = logical ^ (r&7)
        short B[2][BN * BK];  // 2 x 16 KB; row = 32 shorts = 4 chunks of 16B, stored chunk = logical ^ ((n>>1)&3)
    } s;
    short C[BM * CSTR];       // 33.8 KB epilogue staging
};

__global__ __launch_bounds__(256, 3) void gemm1_kernel(const float* __restrict__ x,
                                                       const short* __restrict__ Wt,
                                                       const float* __restrict__ norm_src,
                                                       short* __restrict__ hb, int M) {
    __shared__ __align__(16) SMem sm;
    __shared__ float ns_lds[BM];
    const int tid  = threadIdx.x;
    const int lane = tid & 63;
    const int wave = tid >> 6;
    const int quad = lane >> 4;
    const int mrow = lane & 15;
    const int wm = (wave >> 1) * 32;   // wave row offset (2 row-groups)
    const int wn = (wave & 1) * 128;   // wave col offset (2 col-groups)
    const int bm = blockIdx.x * BM;

    if (tid < BM) ns_lds[tid] = norm_src[min(bm + tid, M - 1)];

    f32x4 acc[2][8] = {};

    // staging lane roles (constant across k)
    const int aL_r = lane >> 3;                       // row within 8-row group
    const int aL_c = (lane & 7) ^ (aL_r & 7);         // logical chunk (swizzle)
    const int bL_r = lane >> 2;                       // row within 16-row group
    const int bL_c = (lane & 3) ^ ((lane >> 3) & 3);  // logical chunk (swizzle)

    auto stageAB = [&](int buf, int k0) {
        // A: 2 instrs/wave, 8 rows each (64 rows total)
#pragma unroll
        for (int i = 0; i < 2; i++) {
            int rowbase = wave * 16 + i * 8;
            int r = rowbase + aL_r;
            if (bm + r < M)
                gload16(x + (size_t)(bm + r) * 1024 + k0 + aL_c * 4, &sm.s.A[buf][rowbase * 32]);
        }
        // B: 4 instrs/wave, 16 rows each (256 rows total)
#pragma unroll
        for (int i = 0; i < 4; i++) {
            int nbase = wave * 64 + i * 16;
            int n = nbase + bL_r;
            gload16(Wt + (size_t)n * 1024 + k0 + bL_c * 8, &sm.s.B[buf][nbase * 32]);
        }
    };

    // prologue: fill buffer 0
    stageAB(0, 0);
    __syncthreads();  // drains vmcnt(0): tile 0 resident

    int cur = 0;
    for (int t = 0; t < NKT; t++) {
        // issue next tile's loads into the other buffer (overlaps with compute below)
        if (t + 1 < NKT) stageAB(cur ^ 1, (t + 1) * BK);

        bf16x8 af[2], bfr[8];
#pragma unroll
        for (int mi = 0; mi < 2; mi++) {
            int row = wm + mi * 16 + mrow;
            f32x4 lo = *(const f32x4*)&sm.s.A[cur][row * 32 + (((quad * 2 + 0) ^ (mrow & 7)) * 4)];
            f32x4 hi = *(const f32x4*)&sm.s.A[cur][row * 32 + (((quad * 2 + 1) ^ (mrow & 7)) * 4)];
            af[mi] = cvt8(lo, hi);
        }
#pragma unroll
        for (int ni = 0; ni < 8; ni++) {
            int n = wn + ni * 16 + mrow;
            bfr[ni] = *(const bf16x8*)&sm.s.B[cur][n * 32 + ((quad ^ ((mrow >> 1) & 3)) * 8)];
        }
#pragma unroll
        for (int mi = 0; mi < 2; mi++)
#pragma unroll
            for (int ni = 0; ni < 8; ni++)
                acc[mi][ni] = __builtin_amdgcn_mfma_f32_16x16x32_bf16(af[mi], bfr[ni], acc[mi][ni], 0, 0, 0);

        // one barrier per K-step: drains prefetch (vmcnt) + joins waves so the
        // buffer we just read can be overwritten next iteration
        __syncthreads();
        cur ^= 1;
    }

    // epilogue: acc -> C LDS (scaled, bf16), then coalesced 16B/lane stores
#pragma unroll
    for (int mi = 0; mi < 2; mi++) {
#pragma unroll
        for (int reg = 0; reg < 4; reg++) {
            int row = wm + mi * 16 + quad * 4 + reg;
            float nsv = ns_lds[row];
#pragma unroll
            for (int ni = 0; ni < 8; ni++) {
                int col = wn + ni * 16 + mrow;
                sm.C[row * CSTR + col] = f2bf(acc[mi][ni][reg] * nsv);
            }
        }
    }
    __syncthreads();
#pragma unroll
    for (int j = 0; j < 8; j++) {
        int row = wave * 2 + (lane >> 5) + j * 8;  // 8 rows/pass x 8 passes = 64
        int chunk = lane & 31;                     // 32 chunks x 8 shorts = 256 cols
        if (bm + row < M) {
            int4 v = *(const int4*)&sm.C[row * CSTR + chunk * 8];
            *(int4*)(hb + (size_t)(bm + row) * 256 + chunk * 8) = v;
        }
    }
}

// ---------- agg1 fused with layer-2 projection ----------
// One wave per node; two edges processed per wave (one per 32-lane half),
// each lane reads 16B (8 bf16) -> 4 x dwordx4 in flight = 8 edges/iter.
__global__ __launch_bounds__(256) void agg1_kernel(const short* __restrict__ hb,
                                                   const int* __restrict__ bucket,
                                                   const int* __restrict__ offsets,
                                                   const float* __restrict__ norm_dst,
                                                   const float* __restrict__ norm_src,
                                                   const float* __restrict__ b1,
                                                   const float* __restrict__ W2,
                                                   float* __restrict__ z, int N) {
    int wave = threadIdx.x >> 6;
    int lane = threadIdx.x & 63;
    int half = lane >> 5;       // which edge of the pair
    int col8 = lane & 31;       // 8-col group within 256
    int node = blockIdx.x * 4 + wave;
    if (node >= N) return;
    int beg = offsets[node], end = offsets[node + 1];
    float a[8] = {0.f, 0.f, 0.f, 0.f, 0.f, 0.f, 0.f, 0.f};
    int e = beg;
    for (; e + 8 <= end; e += 8) {  // 8 edges: 4 gathers of 16B in flight per lane
        int s0 = bucket[e + 0 + half];
        int s1 = bucket[e + 2 + half];
        int s2 = bucket[e + 4 + half];
        int s3 = bucket[e + 6 + half];
        bf16x8 v0 = *(const bf16x8*)(hb + (size_t)s0 * 256 + col8 * 8);
        bf16x8 v1 = *(const bf16x8*)(hb + (size_t)s1 * 256 + col8 * 8);
        bf16x8 v2 = *(const bf16x8*)(hb + (size_t)s2 * 256 + col8 * 8);
        bf16x8 v3 = *(const bf16x8*)(hb + (size_t)s3 * 256 + col8 * 8);
#pragma unroll
        for (int j = 0; j < 8; j++)
            a[j] += bf2f(v0[j]) + bf2f(v1[j]) + bf2f(v2[j]) + bf2f(v3[j]);
    }
    for (; e + 2 <= end; e += 2) {
        int s0 = bucket[e + half];
        bf16x8 v0 = *(const bf16x8*)(hb + (size_t)s0 * 256 + col8 * 8);
#pragma unroll
        for (int j = 0; j < 8; j++) a[j] += bf2f(v0[j]);
    }
    if (e < end && half == 0) {  // single leftover edge, half 0 only
        int s0 = bucket[e];
        bf16x8 v0 = *(const bf16x8*)(hb + (size_t)s0 * 256 + col8 * 8);
#pragma unroll
        for (int j = 0; j < 8; j++) a[j] += bf2f(v0[j]);
    }
    // combine the two half-wave partial sums
#pragma unroll
    for (int j = 0; j < 8; j++) a[j] += __shfl_xor(a[j], 32, 64);

    float nd = norm_dst[node];
    float4 b_lo = *(const float4*)(b1 + col8 * 8);
    float4 b_hi = *(const float4*)(b1 + col8 * 8 + 4);
    float4 w_lo = *(const float4*)(W2 + col8 * 8);
    float4 w_hi = *(const float4*)(W2 + col8 * 8 + 4);
    float p = 0.f;
    p += fmaxf(a[0] * nd + b_lo.x, 0.f) * w_lo.x;
    p += fmaxf(a[1] * nd + b_lo.y, 0.f) * w_lo.y;
    p += fmaxf(a[2] * nd + b_lo.z, 0.f) * w_lo.z;
    p += fmaxf(a[3] * nd + b_lo.w, 0.f) * w_lo.w;
    p += fmaxf(a[4] * nd + b_hi.x, 0.f) * w_hi.x;
    p += fmaxf(a[5] * nd + b_hi.y, 0.f) * w_hi.y;
    p += fmaxf(a[6] * nd + b_hi.z, 0.f) * w_hi.z;
    p += fmaxf(a[7] * nd + b_hi.w, 0.f) * w_hi.w;
#pragma unroll
    for (int off = 16; off > 0; off >>= 1) p += __shfl_xor(p, off, 64);
    if (lane == 0) z[node] = p * norm_src[node];
}

// ---------- agg2: out = relu(norm_dst * sum z[src] + b2) ----------
__global__ void agg2_kernel(const float* __restrict__ z, const int* __restrict__ bucket,
                            const int* __restrict__ offsets, const float* __restrict__ norm_dst,
                            const float* __restrict__ b2, float* __restrict__ out, int N) {
    int i = blockIdx.x * blockDim.x + threadIdx.x;
    if (i >= N) return;
    int beg = offsets[i], end = offsets[i + 1];
    float s = 0.f;
    for (int e = beg; e < end; e++) s += z[bucket[e]];
    out[i] = fmaxf(s * norm_dst[i] + b2[0], 0.f);
}

extern "C" void kernel_launch(void* const* d_in, const int* in_sizes, int n_in,
                              void* d_out, int out_size, void* d_ws, size_t ws_size,
                              hipStream_t stream) {
    const int D_HID = in_sizes[4];           // 256
    const int D_IN  = in_sizes[3] / D_HID;   // 1024
    const int N     = in_sizes[0] / D_IN;    // 50000
    const int E     = in_sizes[1];           // 800000

    const float* x   = (const float*)d_in[0];
    const int*   src = (const int*)d_in[1];
    const int*   dst = (const int*)d_in[2];
    const float* W1  = (const float*)d_in[3];
    const float* b1  = (const float*)d_in[4];
    const float* W2  = (const float*)d_in[5];
    const float* b2  = (const float*)d_in[6];
    float* out = (float*)d_out;

    char* p = (char*)d_ws;
    auto alloc = [&](size_t bytes) {
        void* r = (void*)p;
        p += (bytes + 255) & ~(size_t)255;
        return r;
    };
    int*   deg_out  = (int*)alloc((size_t)N * 4);
    int*   deg_in   = (int*)alloc((size_t)N * 4);
    int*   cursor   = (int*)alloc((size_t)N * 4);
    float* norm_src = (float*)alloc((size_t)N * 4);
    float* norm_dst = (float*)alloc((size_t)N * 4);
    int*   offsets  = (int*)alloc((size_t)(N + 1) * 4);
    int*   bucket   = (int*)alloc((size_t)E * 4);
    short* Wt       = (short*)alloc((size_t)D_IN * D_HID * 2);
    short* hb       = (short*)alloc((size_t)N * D_HID * 2);
    float* z        = (float*)alloc((size_t)N * 4);
    int*   bsum     = (int*)alloc(256 * 4);
    int*   bsum_ex  = (int*)alloc(256 * 4);

    const int NB = (N + 255) / 256;  // 196 scan blocks

    // deg_out, deg_in, cursor are contiguous (256B-aligned) -> one memset
    size_t degpad = ((size_t)N * 4 + 255) & ~(size_t)255;
    hipMemsetAsync(deg_out, 0, degpad * 2 + (size_t)N * 4, stream);

    deg_kernel<<<(E + 255) / 256, 256, 0, stream>>>(src, dst, deg_out, deg_in, E);
    scan_part1<<<NB, 256, 0, stream>>>(deg_in, bsum, N);
    scan_part2<<<1, 256, 0, stream>>>(bsum, bsum_ex, NB, offsets, N, E);
    scan_part3<<<NB, 256, 0, stream>>>(deg_in, deg_out, bsum_ex, offsets, norm_src, norm_dst, N);
    scatter_kernel<<<(E + 255) / 256, 256, 0, stream>>>(src, dst, offsets, cursor, bucket, E);
    transpose_w1<<<dim3(D_IN / 32, D_HID / 32), 1024, 0, stream>>>(W1, Wt);
    gemm1_kernel<<<dim3((N + BM - 1) / BM), 256, 0, stream>>>(x, Wt, norm_src, hb, N);
    agg1_kernel<<<(N + 3) / 4, 256, 0, stream>>>(hb, bucket, offsets, norm_dst, norm_src, b1, W2, z, N);
    agg2_kernel<<<(N + 255) / 256, 256, 0, stream>>>(z, bucket, offsets, norm_dst, b2, out, N);
}

// Round 4
// 488.458 us; speedup vs baseline: 1.0677x; 1.0677x over previous
//
#include <hip/hip_runtime.h>
#include <hip/hip_bf16.h>

// ---------- helpers ----------
typedef __attribute__((ext_vector_type(8))) short bf16x8;
typedef __attribute__((ext_vector_type(4))) float f32x4;

static __device__ __forceinline__ short f2bf(float f) {
    unsigned u = __float_as_uint(f);
    unsigned r = (u + 0x7FFFu + ((u >> 16) & 1u)) >> 16;  // RNE
    return (short)(unsigned short)r;
}
static __device__ __forceinline__ float bf2f(short s) {
    return __uint_as_float(((unsigned)(unsigned short)s) << 16);
}

// async global->LDS, 16B per lane; LDS dest = wave-uniform base + lane*16 (m104)
static __device__ __forceinline__ void gload16(const void* g, void* l) {
    __builtin_amdgcn_global_load_lds((const __attribute__((address_space(1))) unsigned int*)g,
                                     (__attribute__((address_space(3))) unsigned int*)l, 16, 0, 0);
}

// raw workgroup barrier WITHOUT vmcnt(0) drain (unlike __syncthreads).
// Compiler memory fences on both sides prevent LDS access reordering across it.
static __device__ __forceinline__ void wg_barrier() {
    asm volatile("" ::: "memory");
    __builtin_amdgcn_s_barrier();
    asm volatile("" ::: "memory");
}

// pack 8 fp32 -> bf16x8 (RNE, packed cvt where available)
static __device__ __forceinline__ bf16x8 cvt8(const f32x4 lo, const f32x4 hi) {
    __hip_bfloat162 p0 = __float22bfloat162_rn(make_float2(lo[0], lo[1]));
    __hip_bfloat162 p1 = __float22bfloat162_rn(make_float2(lo[2], lo[3]));
    __hip_bfloat162 p2 = __float22bfloat162_rn(make_float2(hi[0], hi[1]));
    __hip_bfloat162 p3 = __float22bfloat162_rn(make_float2(hi[2], hi[3]));
    short2 s0 = *(short2*)&p0, s1 = *(short2*)&p1, s2 = *(short2*)&p2, s3 = *(short2*)&p3;
    bf16x8 r = {s0.x, s0.y, s1.x, s1.y, s2.x, s2.y, s3.x, s3.y};
    return r;
}

// ---------- degree ----------
__global__ void deg_kernel(const int* __restrict__ src, const int* __restrict__ dst,
                           int* __restrict__ deg_out, int* __restrict__ deg_in, int E) {
    int e = blockIdx.x * blockDim.x + threadIdx.x;
    if (e < E) {
        atomicAdd(&deg_out[src[e]], 1);
        atomicAdd(&deg_in[dst[e]], 1);
    }
}

// ---------- 3-phase multi-block exclusive scan of deg_in -> offsets ----------
__global__ void scan_part1(const int* __restrict__ deg, int* __restrict__ bsum, int N) {
    __shared__ int red[256];
    int i = blockIdx.x * 256 + threadIdx.x;
    red[threadIdx.x] = (i < N) ? deg[i] : 0;
    __syncthreads();
    for (int off = 128; off > 0; off >>= 1) {
        if (threadIdx.x < off) red[threadIdx.x] += red[threadIdx.x + off];
        __syncthreads();
    }
    if (threadIdx.x == 0) bsum[blockIdx.x] = red[0];
}

__global__ void scan_part2(const int* __restrict__ bsum, int* __restrict__ bsum_ex, int NB,
                           int* __restrict__ offsets, int N, int E) {
    __shared__ int s[256];
    int t = threadIdx.x;
    int v = (t < NB) ? bsum[t] : 0;
    s[t] = v;
    __syncthreads();
    for (int off = 1; off < 256; off <<= 1) {
        int u = (t >= off) ? s[t - off] : 0;
        __syncthreads();
        s[t] += u;
        __syncthreads();
    }
    bsum_ex[t] = s[t] - v;  // exclusive
    if (t == 0) offsets[N] = E;
}

// scan_part3 + fused norm computation (saves a launch)
__global__ void scan_part3(const int* __restrict__ deg_in, const int* __restrict__ deg_out,
                           const int* __restrict__ bsum_ex, int* __restrict__ offsets,
                           float* __restrict__ ns, float* __restrict__ nd, int N) {
    __shared__ int s[256];
    int t = threadIdx.x, i = blockIdx.x * 256 + t;
    int v = (i < N) ? deg_in[i] : 0;
    s[t] = v;
    __syncthreads();
    for (int off = 1; off < 256; off <<= 1) {
        int u = (t >= off) ? s[t - off] : 0;
        __syncthreads();
        s[t] += u;
        __syncthreads();
    }
    if (i < N) {
        offsets[i] = bsum_ex[blockIdx.x] + s[t] - v;
        ns[i] = rsqrtf((float)max(deg_out[i], 1));
        nd[i] = rsqrtf((float)max(v, 1));
    }
}

// ---------- scatter edges into CSR-by-dst buckets ----------
__global__ void scatter_kernel(const int* __restrict__ src, const int* __restrict__ dst,
                               const int* __restrict__ offsets, int* __restrict__ cursor,
                               int* __restrict__ bucket, int E) {
    int e = blockIdx.x * blockDim.x + threadIdx.x;
    if (e < E) {
        int d = dst[e];
        int p = atomicAdd(&cursor[d], 1);
        bucket[offsets[d] + p] = src[e];
    }
}

// ---------- W1 [K=1024][N=256] fp32 -> Wt [n][k] bf16 ----------
__global__ __launch_bounds__(1024) void transpose_w1(const float* __restrict__ W1,
                                                     short* __restrict__ Wt) {
    __shared__ short tile[32][33];
    int k0 = blockIdx.x * 32, n0 = blockIdx.y * 32;
    int tx = threadIdx.x & 31, ty = threadIdx.x >> 5;
    tile[ty][tx] = f2bf(W1[(size_t)(k0 + ty) * 256 + (n0 + tx)]);
    __syncthreads();
    Wt[(size_t)(n0 + ty) * 1024 + (k0 + tx)] = tile[tx][ty];
}

// ---------- GEMM1: hb = bf16((x @ W1) * norm_src[row]) ----------
// BM=128, BN=256 (full width: x streamed from HBM exactly once).
// Grid = 391 blocks <= 2 blocks/CU x 256 CUs = 512 capacity -> SINGLE resident
// round (the BM=64 version had 782 blocks vs 768 capacity -> straggler round
// doubled the kernel).
// 2-deep pipeline with raw s_barrier + COUNTED s_waitcnt vmcnt(8): tile t+1's
// global_load_lds stays in flight across the barrier (a __syncthreads would
// drain vmcnt(0) and expose full HBM latency every K-step -- measured: dbuf
// with __syncthreads was exactly as slow as no dbuf).
// 4 waves in 2x2 tiling, per-wave 64x128 (acc[4][8]).
#define BM 128
#define BN 256
#define BK 32
#define NKT 32   // 1024 / BK
#define CSTR 264 // C-staging row stride in shorts (528B, 16B-divisible)

union SMem {
    struct {
        float A[2][BM * BK];  // 2 x 16 KB; row = 32 floats = 8 chunks of 16B, stored chunk = logical ^ (r&7)
        short B[2][BN * BK];  // 2 x 16 KB; row = 32 shorts = 4 chunks of 16B, stored chunk = logical ^ ((n>>1)&3)
    } s;
    short C[BM * CSTR];       // 67.6 KB epilogue staging
};

__global__ __launch_bounds__(256, 2) void gemm1_kernel(const float* __restrict__ x,
                                                       const short* __restrict__ Wt,
                                                       const float* __restrict__ norm_src,
                                                       short* __restrict__ hb, int M) {
    __shared__ __align__(16) SMem sm;
    __shared__ float ns_lds[BM];
    const int tid  = threadIdx.x;
    const int lane = tid & 63;
    const int wave = tid >> 6;
    const int quad = lane >> 4;
    const int mrow = lane & 15;
    const int wm = (wave >> 1) * 64;   // wave row offset (2 row-groups of 64)
    const int wn = (wave & 1) * 128;   // wave col offset (2 col-groups of 128)
    const int bm = blockIdx.x * BM;

    if (tid < BM) ns_lds[tid] = norm_src[min(bm + tid, M - 1)];

    f32x4 acc[4][8] = {};

    // staging lane roles (constant across k)
    const int aL_r = lane >> 3;                       // row within 8-row group
    const int aL_c = (lane & 7) ^ (aL_r & 7);         // logical chunk (swizzle)
    const int bL_r = lane >> 2;                       // row within 16-row group
    const int bL_c = (lane & 3) ^ ((lane >> 3) & 3);  // logical chunk (swizzle)

    // 8 loads/stage/wave, UNCONDITIONAL (row clamped, so vmcnt counts are
    // uniform across waves; out-of-range rows are garbage, masked at C-write)
    auto stageAB = [&](int buf, int k0) {
        // A: 4 instrs/wave, 8 rows each (128 rows total)
#pragma unroll
        for (int i = 0; i < 4; i++) {
            int rowbase = wave * 32 + i * 8;
            int r = min(bm + rowbase + aL_r, M - 1);
            gload16(x + (size_t)r * 1024 + k0 + aL_c * 4, &sm.s.A[buf][rowbase * 32]);
        }
        // B: 4 instrs/wave, 16 rows each (256 rows total)
#pragma unroll
        for (int i = 0; i < 4; i++) {
            int nbase = wave * 64 + i * 16;
            int n = nbase + bL_r;
            gload16(Wt + (size_t)n * 1024 + k0 + bL_c * 8, &sm.s.B[buf][nbase * 32]);
        }
    };

    // prologue: fill both buffers; wait only for tile 0 (8 newest stay in flight)
    stageAB(0, 0);
    stageAB(1, BK);
    asm volatile("s_waitcnt vmcnt(8)" ::: "memory");
    wg_barrier();

    int cur = 0;
    for (int t = 0; t < NKT; t++) {
        // ---- compute tile t from buf[cur] ----
        bf16x8 af[4], bfr[8];
#pragma unroll
        for (int mi = 0; mi < 4; mi++) {
            int row = wm + mi * 16 + mrow;
            f32x4 lo = *(const f32x4*)&sm.s.A[cur][row * 32 + (((quad * 2 + 0) ^ (mrow & 7)) * 4)];
            f32x4 hi = *(const f32x4*)&sm.s.A[cur][row * 32 + (((quad * 2 + 1) ^ (mrow & 7)) * 4)];
            af[mi] = cvt8(lo, hi);
        }
#pragma unroll
        for (int ni = 0; ni < 8; ni++) {
            int n = wn + ni * 16 + mrow;
            bfr[ni] = *(const bf16x8*)&sm.s.B[cur][n * 32 + ((quad ^ ((mrow >> 1) & 3)) * 8)];
        }
#pragma unroll
        for (int mi = 0; mi < 4; mi++)
#pragma unroll
            for (int ni = 0; ni < 8; ni++)
                acc[mi][ni] = __builtin_amdgcn_mfma_f32_16x16x32_bf16(af[mi], bfr[ni], acc[mi][ni], 0, 0, 0);

        // all waves done reading buf[cur] (each wave's ds_reads were consumed
        // by its MFMAs before arriving) -> safe to overwrite buf[cur]
        wg_barrier();

        if (t + 2 < NKT) {
            stageAB(cur, (t + 2) * BK);                      // 8 new loads
            asm volatile("s_waitcnt vmcnt(8)" ::: "memory"); // oldest 8 = tile t+1 landed
        } else {
            asm volatile("s_waitcnt vmcnt(0)" ::: "memory"); // drain remaining
        }
        // all waves' tile-(t+1) loads landed -> buf[cur^1] fully resident
        wg_barrier();
        cur ^= 1;
    }

    // epilogue: acc -> C LDS (scaled, bf16), then coalesced 16B/lane stores.
    // Last loop barrier guarantees union A/B regions are dead.
#pragma unroll
    for (int mi = 0; mi < 4; mi++) {
#pragma unroll
        for (int reg = 0; reg < 4; reg++) {
            int row = wm + mi * 16 + quad * 4 + reg;
            float nsv = ns_lds[row];
#pragma unroll
            for (int ni = 0; ni < 8; ni++) {
                int col = wn + ni * 16 + mrow;
                sm.C[row * CSTR + col] = f2bf(acc[mi][ni][reg] * nsv);
            }
        }
    }
    __syncthreads();
#pragma unroll
    for (int j = 0; j < 16; j++) {
        int row = wave * 2 + (lane >> 5) + j * 8;  // 8 rows/pass x 16 passes = 128
        int chunk = lane & 31;                     // 32 chunks x 8 shorts = 256 cols
        if (bm + row < M) {
            int4 v = *(const int4*)&sm.C[row * CSTR + chunk * 8];
            *(int4*)(hb + (size_t)(bm + row) * 256 + chunk * 8) = v;
        }
    }
}

// ---------- agg1 fused with layer-2 projection ----------
// One wave per node; two edges processed per wave (one per 32-lane half),
// each lane reads 16B (8 bf16) -> 4 x dwordx4 in flight = 8 edges/iter.
__global__ __launch_bounds__(256) void agg1_kernel(const short* __restrict__ hb,
                                                   const int* __restrict__ bucket,
                                                   const int* __restrict__ offsets,
                                                   const float* __restrict__ norm_dst,
                                                   const float* __restrict__ norm_src,
                                                   const float* __restrict__ b1,
                                                   const float* __restrict__ W2,
                                                   float* __restrict__ z, int N) {
    int wave = threadIdx.x >> 6;
    int lane = threadIdx.x & 63;
    int half = lane >> 5;       // which edge of the pair
    int col8 = lane & 31;       // 8-col group within 256
    int node = blockIdx.x * 4 + wave;
    if (node >= N) return;
    int beg = offsets[node], end = offsets[node + 1];
    float a[8] = {0.f, 0.f, 0.f, 0.f, 0.f, 0.f, 0.f, 0.f};
    int e = beg;
    for (; e + 8 <= end; e += 8) {  // 8 edges: 4 gathers of 16B in flight per lane
        int s0 = bucket[e + 0 + half];
        int s1 = bucket[e + 2 + half];
        int s2 = bucket[e + 4 + half];
        int s3 = bucket[e + 6 + half];
        bf16x8 v0 = *(const bf16x8*)(hb + (size_t)s0 * 256 + col8 * 8);
        bf16x8 v1 = *(const bf16x8*)(hb + (size_t)s1 * 256 + col8 * 8);
        bf16x8 v2 = *(const bf16x8*)(hb + (size_t)s2 * 256 + col8 * 8);
        bf16x8 v3 = *(const bf16x8*)(hb + (size_t)s3 * 256 + col8 * 8);
#pragma unroll
        for (int j = 0; j < 8; j++)
            a[j] += bf2f(v0[j]) + bf2f(v1[j]) + bf2f(v2[j]) + bf2f(v3[j]);
    }
    for (; e + 2 <= end; e += 2) {
        int s0 = bucket[e + half];
        bf16x8 v0 = *(const bf16x8*)(hb + (size_t)s0 * 256 + col8 * 8);
#pragma unroll
        for (int j = 0; j < 8; j++) a[j] += bf2f(v0[j]);
    }
    if (e < end && half == 0) {  // single leftover edge, half 0 only
        int s0 = bucket[e];
        bf16x8 v0 = *(const bf16x8*)(hb + (size_t)s0 * 256 + col8 * 8);
#pragma unroll
        for (int j = 0; j < 8; j++) a[j] += bf2f(v0[j]);
    }
    // combine the two half-wave partial sums
#pragma unroll
    for (int j = 0; j < 8; j++) a[j] += __shfl_xor(a[j], 32, 64);

    float nd = norm_dst[node];
    float4 b_lo = *(const float4*)(b1 + col8 * 8);
    float4 b_hi = *(const float4*)(b1 + col8 * 8 + 4);
    float4 w_lo = *(const float4*)(W2 + col8 * 8);
    float4 w_hi = *(const float4*)(W2 + col8 * 8 + 4);
    float p = 0.f;
    p += fmaxf(a[0] * nd + b_lo.x, 0.f) * w_lo.x;
    p += fmaxf(a[1] * nd + b_lo.y, 0.f) * w_lo.y;
    p += fmaxf(a[2] * nd + b_lo.z, 0.f) * w_lo.z;
    p += fmaxf(a[3] * nd + b_lo.w, 0.f) * w_lo.w;
    p += fmaxf(a[4] * nd + b_hi.x, 0.f) * w_hi.x;
    p += fmaxf(a[5] * nd + b_hi.y, 0.f) * w_hi.y;
    p += fmaxf(a[6] * nd + b_hi.z, 0.f) * w_hi.z;
    p += fmaxf(a[7] * nd + b_hi.w, 0.f) * w_hi.w;
#pragma unroll
    for (int off = 16; off > 0; off >>= 1) p += __shfl_xor(p, off, 64);
    if (lane == 0) z[node] = p * norm_src[node];
}

// ---------- agg2: out = relu(norm_dst * sum z[src] + b2) ----------
__global__ void agg2_kernel(const float* __restrict__ z, const int* __restrict__ bucket,
                            const int* __restrict__ offsets, const float* __restrict__ norm_dst,
                            const float* __restrict__ b2, float* __restrict__ out, int N) {
    int i = blockIdx.x * blockDim.x + threadIdx.x;
    if (i >= N) return;
    int beg = offsets[i], end = offsets[i + 1];
    float s = 0.f;
    for (int e = beg; e < end; e++) s += z[bucket[e]];
    out[i] = fmaxf(s * norm_dst[i] + b2[0], 0.f);
}

extern "C" void kernel_launch(void* const* d_in, const int* in_sizes, int n_in,
                              void* d_out, int out_size, void* d_ws, size_t ws_size,
                              hipStream_t stream) {
    const int D_HID = in_sizes[4];           // 256
    const int D_IN  = in_sizes[3] / D_HID;   // 1024
    const int N     = in_sizes[0] / D_IN;    // 50000
    const int E     = in_sizes[1];           // 800000

    const float* x   = (const float*)d_in[0];
    const int*   src = (const int*)d_in[1];
    const int*   dst = (const int*)d_in[2];
    const float* W1  = (const float*)d_in[3];
    const float* b1  = (const float*)d_in[4];
    const float* W2  = (const float*)d_in[5];
    const float* b2  = (const float*)d_in[6];
    float* out = (float*)d_out;

    char* p = (char*)d_ws;
    auto alloc = [&](size_t bytes) {
        void* r = (void*)p;
        p += (bytes + 255) & ~(size_t)255;
        return r;
    };
    int*   deg_out  = (int*)alloc((size_t)N * 4);
    int*   deg_in   = (int*)alloc((size_t)N * 4);
    int*   cursor   = (int*)alloc((size_t)N * 4);
    float* norm_src = (float*)alloc((size_t)N * 4);
    float* norm_dst = (float*)alloc((size_t)N * 4);
    int*   offsets  = (int*)alloc((size_t)(N + 1) * 4);
    int*   bucket   = (int*)alloc((size_t)E * 4);
    short* Wt       = (short*)alloc((size_t)D_IN * D_HID * 2);
    short* hb       = (short*)alloc((size_t)N * D_HID * 2);
    float* z        = (float*)alloc((size_t)N * 4);
    int*   bsum     = (int*)alloc(256 * 4);
    int*   bsum_ex  = (int*)alloc(256 * 4);

    const int NB = (N + 255) / 256;  // 196 scan blocks

    // deg_out, deg_in, cursor are contiguous (256B-aligned) -> one memset
    size_t degpad = ((size_t)N * 4 + 255) & ~(size_t)255;
    hipMemsetAsync(deg_out, 0, degpad * 2 + (size_t)N * 4, stream);

    deg_kernel<<<(E + 255) / 256, 256, 0, stream>>>(src, dst, deg_out, deg_in, E);
    scan_part1<<<NB, 256, 0, stream>>>(deg_in, bsum, N);
    scan_part2<<<1, 256, 0, stream>>>(bsum, bsum_ex, NB, offsets, N, E);
    scan_part3<<<NB, 256, 0, stream>>>(deg_in, deg_out, bsum_ex, offsets, norm_src, norm_dst, N);
    scatter_kernel<<<(E + 255) / 256, 256, 0, stream>>>(src, dst, offsets, cursor, bucket, E);
    transpose_w1<<<dim3(D_IN / 32, D_HID / 32), 1024, 0, stream>>>(W1, Wt);
    gemm1_kernel<<<dim3((N + BM - 1) / BM), 256, 0, stream>>>(x, Wt, norm_src, hb, N);
    agg1_kernel<<<(N + 3) / 4, 256, 0, stream>>>(hb, bucket, offsets, norm_dst, norm_src, b1, W2, z, N);
    agg2_kernel<<<(N + 255) / 256, 256, 0, stream>>>(z, bucket, offsets, norm_dst, b2, out, N);
}